// Round 6
// baseline (4299.290 us; speedup 1.0000x reference)
//
#include <hip/hip_runtime.h>

// LSTM: B=128, T=512, I=64, H=512, O=1, fp32 in/out.
// 64 persistent WGs = 8 jg x 8 bg; 256 threads; waves fully decoupled:
// per-wave flags, NO LDS, NO __syncthreads in the loop.
// All cross-WG exchange uses R4-proven encodings only:
//   flags: __hip_atomic_load/store (relaxed, AGENT scope)
//   h data: inline-asm global ops with "sc0 sc1" (L3 coherence point)
// h loads batched (32 dwordx4) + x(t+1) register prefetch, consumed via
// counted vmcnt waits. Projection partials via atomicAdd after the flag.

#define B_ 128
#define T_ 512
#define I_ 64
#define H_ 512

typedef __attribute__((ext_vector_type(8))) short short8;   // 8 bf16
typedef __attribute__((ext_vector_type(4))) float f32x4;
typedef __attribute__((ext_vector_type(4))) unsigned u32x4;

__device__ inline unsigned f2bf_u(float f) {
  union { float f; unsigned u; } v; v.f = f;
  return (v.u + 0x7fffu + ((v.u >> 16) & 1u)) >> 16;  // RNE
}
__device__ inline float bf2f(unsigned s) {
  union { unsigned u; float f; } v; v.u = s << 16; return v.f;
}
__device__ inline float sigm(float x) { return 1.0f / (1.0f + __expf(-x)); }
__device__ inline float tanh_(float x) { return 1.0f - 2.0f / (1.0f + __expf(2.0f * x)); }

#define WAITV(N)                                        \
  asm volatile("s_waitcnt vmcnt(" #N ")" ::: "memory"); \
  __builtin_amdgcn_sched_barrier(0)

// coherent 16B load at L3 point (R4-proven)
#define HLOADQ(dst, base, OFF)                                            \
  asm volatile("global_load_dwordx4 %0, %1, off offset:" #OFF " sc0 sc1"  \
               : "=v"(dst) : "v"(base))

// x: read-only input, normal cached path
#define XLOADQ(dst, base, OFF)                                            \
  asm volatile("global_load_dwordx4 %0, %1, off offset:" #OFF             \
               : "=v"(dst) : "v"(base))

// coherent 2B store at L3 point
#define HSTORES(base, val, OFF)                                           \
  asm volatile("global_store_short %0, %1, off offset:" #OFF " sc0 sc1"   \
               :: "v"(base), "v"(val) : "memory")

__global__ __launch_bounds__(256, 1) void lstm_kernel(
    const float* __restrict__ x,    // [B,T,I]
    const float* __restrict__ Wih,  // [4H,I]
    const float* __restrict__ Whh,  // [4H,H]
    const float* __restrict__ bih,  // [4H]
    const float* __restrict__ bhh,  // [4H]
    const float* __restrict__ Who,  // [1,H]
    float* __restrict__ part,       // [B][T] fp32 partial sums (atomicAdd)
    unsigned short* __restrict__ hbuf,  // 2 bufs x (hi[B][H], lo[B][H]) bf16
    unsigned* __restrict__ flags)       // 8 bg x 32 per-wave flags
{
  const int bid = blockIdx.x;
  const int jg = bid >> 3;      // 0..7  hidden group (64 j)
  const int bg = bid & 7;       // 0..7  batch group (16 b)
  const int tid = threadIdx.x;
  const int w = tid >> 6;       // wave 0..3
  const int l = tid & 63;
  const int l16 = l & 15;
  const int lk = l >> 4;        // 0..3
  const int b = bg * 16 + l16;

  // ---- resident weights: bf16 A-frags, 4 M-tiles/wave ----
  short8 a_hh[4][16], a_ih[4][2];
  float bias[4][4], who[4];
#pragma unroll
  for (int m = 0; m < 4; ++m) {
    const int rowA = w * 64 + m * 16 + l16;                    // WG row = jl*4+gate
    const int grow = (rowA & 3) * 512 + jg * 64 + (rowA >> 2); // global gate row
#pragma unroll
    for (int kt = 0; kt < 16; ++kt) {
      const float* p = Whh + (size_t)grow * H_ + kt * 32 + lk * 8;
      short8 s;
#pragma unroll
      for (int e = 0; e < 8; ++e) s[e] = (short)f2bf_u(p[e]);
      a_hh[m][kt] = s;
    }
#pragma unroll
    for (int kt = 0; kt < 2; ++kt) {
      const float* p = Wih + (size_t)grow * I_ + kt * 32 + lk * 8;
      short8 s;
#pragma unroll
      for (int e = 0; e < 8; ++e) s[e] = (short)f2bf_u(p[e]);
      a_ih[m][kt] = s;
    }
    const int jm = jg * 64 + w * 16 + m * 4 + lk;
#pragma unroll
    for (int g = 0; g < 4; ++g) bias[m][g] = bih[g * 512 + jm] + bhh[g * 512 + jm];
    who[m] = Who[jm];
  }

  unsigned short* const hb0 = hbuf;
  unsigned short* const hb1 = hbuf + 2 * B_ * H_;
  unsigned* const fbase = flags + (size_t)bg * 32;
  unsigned* const myflag = fbase + (jg * 4 + w);
  const float* const xrow = x + (size_t)b * (T_ * I_);

  float c[4] = {0.f, 0.f, 0.f, 0.f};
  f32x4 xf0, xf1, xf2, xf3;
  {
    const float* xb = xrow + lk * 8;   // t = 0
    XLOADQ(xf0, xb, 0);   XLOADQ(xf1, xb, 16);
    XLOADQ(xf2, xb, 128); XLOADQ(xf3, xb, 144);
    WAITV(0);
  }

  for (int t = 0; t < T_; ++t) {
    const int pr = t & 1;
    const unsigned short* hp = pr ? hb1 : hb0;
    unsigned short* hn       = pr ? hb0 : hb1;

    f32x4 acc[4][2];
#pragma unroll
    for (int m = 0; m < 4; ++m) {
      acc[m][0] = (f32x4){0.f, 0.f, 0.f, 0.f};
      acc[m][1] = (f32x4){0.f, 0.f, 0.f, 0.f};
    }

    // ---- x projection from prefetched regs (pure VALU+MFMA) ----
#pragma unroll
    for (int kt = 0; kt < 2; ++kt) {
      f32x4 va = kt ? xf2 : xf0;
      f32x4 vb = kt ? xf3 : xf1;
      float v[8] = {va[0], va[1], va[2], va[3], vb[0], vb[1], vb[2], vb[3]};
      short8 xhi, xlo;
#pragma unroll
      for (int e = 0; e < 8; ++e) {
        unsigned hb = f2bf_u(v[e]);
        xhi[e] = (short)hb;
        xlo[e] = (short)f2bf_u(v[e] - bf2f(hb));
      }
#pragma unroll
      for (int m = 0; m < 4; ++m) {
        acc[m][0] = __builtin_amdgcn_mfma_f32_16x16x32_bf16(a_ih[m][kt], xhi, acc[m][0], 0, 0, 0);
        acc[m][1] = __builtin_amdgcn_mfma_f32_16x16x32_bf16(a_ih[m][kt], xlo, acc[m][1], 0, 0, 0);
      }
    }

    // ---- poll: all 32 producer waves of this bg finished step t-1 ----
    if (t > 0) {
      const unsigned* fp = fbase + (l & 31);
      for (;;) {
        unsigned f = __hip_atomic_load(fp, __ATOMIC_RELAXED, __HIP_MEMORY_SCOPE_AGENT);
        if (__all(f >= (unsigned)t)) break;
      }
    }
    __builtin_amdgcn_fence(__ATOMIC_ACQUIRE, "workgroup");  // compiler order only
    __builtin_amdgcn_sched_barrier(0);

    // ---- batch-issue: 32 h loads + 4 x(t+1) loads; counted consumption ----
    u32x4 hh[16], hl[16];
    {
      const unsigned short* phi = hp + (size_t)b * H_ + lk * 8;
      const unsigned short* plo = phi + (size_t)(B_ * H_);
      HLOADQ(hh[0],  phi, 0);    HLOADQ(hl[0],  plo, 0);
      HLOADQ(hh[1],  phi, 64);   HLOADQ(hl[1],  plo, 64);
      HLOADQ(hh[2],  phi, 128);  HLOADQ(hl[2],  plo, 128);
      HLOADQ(hh[3],  phi, 192);  HLOADQ(hl[3],  plo, 192);
      HLOADQ(hh[4],  phi, 256);  HLOADQ(hl[4],  plo, 256);
      HLOADQ(hh[5],  phi, 320);  HLOADQ(hl[5],  plo, 320);
      HLOADQ(hh[6],  phi, 384);  HLOADQ(hl[6],  plo, 384);
      HLOADQ(hh[7],  phi, 448);  HLOADQ(hl[7],  plo, 448);
      HLOADQ(hh[8],  phi, 512);  HLOADQ(hl[8],  plo, 512);
      HLOADQ(hh[9],  phi, 576);  HLOADQ(hl[9],  plo, 576);
      HLOADQ(hh[10], phi, 640);  HLOADQ(hl[10], plo, 640);
      HLOADQ(hh[11], phi, 704);  HLOADQ(hl[11], plo, 704);
      HLOADQ(hh[12], phi, 768);  HLOADQ(hl[12], plo, 768);
      HLOADQ(hh[13], phi, 832);  HLOADQ(hl[13], plo, 832);
      HLOADQ(hh[14], phi, 896);  HLOADQ(hl[14], plo, 896);
      HLOADQ(hh[15], phi, 960);  HLOADQ(hl[15], plo, 960);
      const int tn = (t + 1 < T_) ? t + 1 : t;   // uniform vmem op count
      const float* xb = xrow + tn * I_ + lk * 8;
      XLOADQ(xf0, xb, 0);   XLOADQ(xf1, xb, 16);
      XLOADQ(xf2, xb, 128); XLOADQ(xf3, xb, 144);
    }
#define MFMA_CHUNK(cc)                                                        \
    _Pragma("unroll")                                                         \
    for (int k2 = 0; k2 < 4; ++k2) {                                          \
      const int kt = (cc) * 4 + k2;                                           \
      union { u32x4 u; short8 s; } uh, ul;                                    \
      uh.u = hh[kt]; ul.u = hl[kt];                                           \
      _Pragma("unroll")                                                       \
      for (int m = 0; m < 4; ++m) {                                           \
        acc[m][0] = __builtin_amdgcn_mfma_f32_16x16x32_bf16(a_hh[m][kt], uh.s, acc[m][0], 0, 0, 0); \
        acc[m][1] = __builtin_amdgcn_mfma_f32_16x16x32_bf16(a_hh[m][kt], ul.s, acc[m][1], 0, 0, 0); \
      }                                                                       \
    }
    WAITV(28); MFMA_CHUNK(0)
    WAITV(20); MFMA_CHUNK(1)
    WAITV(12); MFMA_CHUNK(2)
    WAITV(4);  MFMA_CHUNK(3)
#undef MFMA_CHUNK

    // ---- pointwise (lane-local: 4 cells x 4 gates) ----
    float p = 0.f;
    unsigned vhi[4], vlo[4];
#pragma unroll
    for (int m = 0; m < 4; ++m) {
      float gi = sigm(acc[m][0].x + acc[m][1].x + bias[m][0]);
      float gf = sigm(acc[m][0].y + acc[m][1].y + bias[m][1]);
      float gg = tanh_(acc[m][0].z + acc[m][1].z + bias[m][2]);
      float go = sigm(acc[m][0].w + acc[m][1].w + bias[m][3]);
      c[m] = gf * c[m] + gi * gg;
      float hv = go * tanh_(c[m]);
      p += hv * who[m];
      unsigned hb = f2bf_u(hv);
      vhi[m] = hb;
      vlo[m] = f2bf_u(hv - bf2f(hb));
    }

    // ---- h stores straight from registers ----
    {
      unsigned short* ph  = hn + (size_t)b * H_ + jg * 64 + w * 16 + lk;
      unsigned short* pl2 = ph + (size_t)(B_ * H_);
      HSTORES(ph,  vhi[0], 0);  HSTORES(ph,  vhi[1], 8);
      HSTORES(ph,  vhi[2], 16); HSTORES(ph,  vhi[3], 24);
      HSTORES(pl2, vlo[0], 0);  HSTORES(pl2, vlo[1], 8);
      HSTORES(pl2, vlo[2], 16); HSTORES(pl2, vlo[3], 24);
    }

    WAITV(0);  // h stores acked at L3; x(t+1) regs ready
    if (l == 0)
      __hip_atomic_store(myflag, (unsigned)(t + 1),
                         __ATOMIC_RELAXED, __HIP_MEMORY_SCOPE_AGENT);

    // ---- projection partial (off critical path, after flag) ----
    p += __shfl_xor(p, 16);
    p += __shfl_xor(p, 32);          // sum over this wave's 16 j
    if (l < 16) atomicAdd(part + (size_t)b * T_ + t, p);
  }
}

__global__ __launch_bounds__(256) void reduce_out(const float* __restrict__ part,
                                                  const float* __restrict__ b_ho,
                                                  float* __restrict__ out) {
  int i = blockIdx.x * blockDim.x + threadIdx.x;
  if (i < B_ * T_) out[i] = part[i] + b_ho[0];
}

extern "C" void kernel_launch(void* const* d_in, const int* in_sizes, int n_in,
                              void* d_out, int out_size, void* d_ws, size_t ws_size,
                              hipStream_t stream) {
  (void)in_sizes; (void)n_in; (void)out_size; (void)ws_size;
  const float* x   = (const float*)d_in[0];
  const float* Wih = (const float*)d_in[1];
  const float* Whh = (const float*)d_in[2];
  const float* bih = (const float*)d_in[3];
  const float* bhh = (const float*)d_in[4];
  const float* Who = (const float*)d_in[5];
  const float* bho = (const float*)d_in[6];
  float* out = (float*)d_out;

  // ws: hbuf 512KB | part 256KB | flags 1KB
  unsigned short* hbuf = (unsigned short*)d_ws;
  const size_t hbytes = (size_t)2 * 2 * B_ * H_ * sizeof(unsigned short);
  float* part = (float*)((char*)d_ws + hbytes);
  const size_t pbytes = (size_t)B_ * T_ * sizeof(float);
  unsigned* flags = (unsigned*)((char*)d_ws + hbytes + pbytes);

  hipMemsetAsync(d_ws, 0, hbytes + pbytes + 8 * 32 * sizeof(unsigned), stream);

  lstm_kernel<<<dim3(64), dim3(256), 0, stream>>>(x, Wih, Whh, bih, bhh, Who,
                                                  part, hbuf, flags);
  reduce_out<<<(B_ * T_ + 255) / 256, 256, 0, stream>>>(part, bho, out);
}

// Round 7
// 3404.860 us; speedup vs baseline: 1.2627x; 1.2627x over previous
//
#include <hip/hip_runtime.h>

// LSTM: B=128, T=512, I=64, H=512, O=1, fp32 in/out.
// 64 persistent WGs = 8 jg x 8 bg; 256 threads; waves fully decoupled:
// per-wave flags, NO LDS, NO __syncthreads in the loop.
// Cross-WG exchange (R4/R6-proven encodings):
//   flags: __hip_atomic_load/store (relaxed, AGENT scope)
//   h data: inline-asm global ops with "sc0 sc1" (L3 coherence point)
// R7: h stores coalesced WITHOUT LDS — in-register 4x4 transpose across the
// lk sub-lanes (2 shfl_xor stages), then one 8B dwordx2 store per plane per
// lane (4 lanes = contiguous 32B sector; kills subword write amplification).

#define B_ 128
#define T_ 512
#define I_ 64
#define H_ 512

typedef __attribute__((ext_vector_type(8))) short short8;   // 8 bf16
typedef __attribute__((ext_vector_type(4))) float f32x4;
typedef __attribute__((ext_vector_type(4))) unsigned u32x4;

__device__ inline unsigned f2bf_u(float f) {
  union { float f; unsigned u; } v; v.f = f;
  return (v.u + 0x7fffu + ((v.u >> 16) & 1u)) >> 16;  // RNE
}
__device__ inline float bf2f(unsigned s) {
  union { unsigned u; float f; } v; v.u = s << 16; return v.f;
}
__device__ inline float sigm(float x) { return 1.0f / (1.0f + __expf(-x)); }
__device__ inline float tanh_(float x) { return 1.0f - 2.0f / (1.0f + __expf(2.0f * x)); }

#define WAITV(N)                                        \
  asm volatile("s_waitcnt vmcnt(" #N ")" ::: "memory"); \
  __builtin_amdgcn_sched_barrier(0)

// coherent 16B load at L3 point (R4-proven)
#define HLOADQ(dst, base, OFF)                                            \
  asm volatile("global_load_dwordx4 %0, %1, off offset:" #OFF " sc0 sc1"  \
               : "=v"(dst) : "v"(base))

// x: read-only input, normal cached path
#define XLOADQ(dst, base, OFF)                                            \
  asm volatile("global_load_dwordx4 %0, %1, off offset:" #OFF             \
               : "=v"(dst) : "v"(base))

// coherent 8B store at L3 point (coalesced: 4 lanes -> 32B sector)
#define HSTORED2(base, v64)                                               \
  asm volatile("global_store_dwordx2 %0, %1, off sc0 sc1"                 \
               :: "v"(base), "v"(v64) : "memory")

__global__ __launch_bounds__(256, 1) void lstm_kernel(
    const float* __restrict__ x,    // [B,T,I]
    const float* __restrict__ Wih,  // [4H,I]
    const float* __restrict__ Whh,  // [4H,H]
    const float* __restrict__ bih,  // [4H]
    const float* __restrict__ bhh,  // [4H]
    const float* __restrict__ Who,  // [1,H]
    float* __restrict__ part,       // [B][T] fp32 partial sums (atomicAdd)
    unsigned short* __restrict__ hbuf,  // 2 bufs x (hi[B][H], lo[B][H]) bf16
    unsigned* __restrict__ flags)       // 8 bg x 32 per-wave flags
{
  const int bid = blockIdx.x;
  const int jg = bid >> 3;      // 0..7  hidden group (64 j)
  const int bg = bid & 7;       // 0..7  batch group (16 b)
  const int tid = threadIdx.x;
  const int w = tid >> 6;       // wave 0..3
  const int l = tid & 63;
  const int l16 = l & 15;
  const int lk = l >> 4;        // 0..3
  const int b = bg * 16 + l16;

  // ---- resident weights: bf16 A-frags, 4 M-tiles/wave ----
  short8 a_hh[4][16], a_ih[4][2];
  float bias[4][4], who[4];
#pragma unroll
  for (int m = 0; m < 4; ++m) {
    const int rowA = w * 64 + m * 16 + l16;                    // WG row = jl*4+gate
    const int grow = (rowA & 3) * 512 + jg * 64 + (rowA >> 2); // global gate row
#pragma unroll
    for (int kt = 0; kt < 16; ++kt) {
      const float* p = Whh + (size_t)grow * H_ + kt * 32 + lk * 8;
      short8 s;
#pragma unroll
      for (int e = 0; e < 8; ++e) s[e] = (short)f2bf_u(p[e]);
      a_hh[m][kt] = s;
    }
#pragma unroll
    for (int kt = 0; kt < 2; ++kt) {
      const float* p = Wih + (size_t)grow * I_ + kt * 32 + lk * 8;
      short8 s;
#pragma unroll
      for (int e = 0; e < 8; ++e) s[e] = (short)f2bf_u(p[e]);
      a_ih[m][kt] = s;
    }
    const int jm = jg * 64 + w * 16 + m * 4 + lk;
#pragma unroll
    for (int g = 0; g < 4; ++g) bias[m][g] = bih[g * 512 + jm] + bhh[g * 512 + jm];
    who[m] = Who[jm];
  }

  unsigned short* const hb0 = hbuf;
  unsigned short* const hb1 = hbuf + 2 * B_ * H_;
  unsigned* const fbase = flags + (size_t)bg * 32;
  unsigned* const myflag = fbase + (jg * 4 + w);
  const float* const xrow = x + (size_t)b * (T_ * I_);

  float c[4] = {0.f, 0.f, 0.f, 0.f};
  f32x4 xf0, xf1, xf2, xf3;
  {
    const float* xb = xrow + lk * 8;   // t = 0
    XLOADQ(xf0, xb, 0);   XLOADQ(xf1, xb, 16);
    XLOADQ(xf2, xb, 128); XLOADQ(xf3, xb, 144);
    WAITV(0);
  }

  for (int t = 0; t < T_; ++t) {
    const int pr = t & 1;
    const unsigned short* hp = pr ? hb1 : hb0;
    unsigned short* hn       = pr ? hb0 : hb1;

    f32x4 acc[4][2];
#pragma unroll
    for (int m = 0; m < 4; ++m) {
      acc[m][0] = (f32x4){0.f, 0.f, 0.f, 0.f};
      acc[m][1] = (f32x4){0.f, 0.f, 0.f, 0.f};
    }

    // ---- x projection from prefetched regs (pure VALU+MFMA) ----
#pragma unroll
    for (int kt = 0; kt < 2; ++kt) {
      f32x4 va = kt ? xf2 : xf0;
      f32x4 vb = kt ? xf3 : xf1;
      float v[8] = {va[0], va[1], va[2], va[3], vb[0], vb[1], vb[2], vb[3]};
      short8 xhi, xlo;
#pragma unroll
      for (int e = 0; e < 8; ++e) {
        unsigned hb = f2bf_u(v[e]);
        xhi[e] = (short)hb;
        xlo[e] = (short)f2bf_u(v[e] - bf2f(hb));
      }
#pragma unroll
      for (int m = 0; m < 4; ++m) {
        acc[m][0] = __builtin_amdgcn_mfma_f32_16x16x32_bf16(a_ih[m][kt], xhi, acc[m][0], 0, 0, 0);
        acc[m][1] = __builtin_amdgcn_mfma_f32_16x16x32_bf16(a_ih[m][kt], xlo, acc[m][1], 0, 0, 0);
      }
    }

    // ---- poll: all 32 producer waves of this bg finished step t-1 ----
    if (t > 0) {
      const unsigned* fp = fbase + (l & 31);
      for (;;) {
        unsigned f = __hip_atomic_load(fp, __ATOMIC_RELAXED, __HIP_MEMORY_SCOPE_AGENT);
        if (__all(f >= (unsigned)t)) break;
      }
    }
    __builtin_amdgcn_fence(__ATOMIC_ACQUIRE, "workgroup");  // compiler order only
    __builtin_amdgcn_sched_barrier(0);

    // ---- batch-issue: 32 h loads + 4 x(t+1) loads; counted consumption ----
    u32x4 hh[16], hl[16];
    {
      const unsigned short* phi = hp + (size_t)b * H_ + lk * 8;
      const unsigned short* plo = phi + (size_t)(B_ * H_);
      HLOADQ(hh[0],  phi, 0);    HLOADQ(hl[0],  plo, 0);
      HLOADQ(hh[1],  phi, 64);   HLOADQ(hl[1],  plo, 64);
      HLOADQ(hh[2],  phi, 128);  HLOADQ(hl[2],  plo, 128);
      HLOADQ(hh[3],  phi, 192);  HLOADQ(hl[3],  plo, 192);
      HLOADQ(hh[4],  phi, 256);  HLOADQ(hl[4],  plo, 256);
      HLOADQ(hh[5],  phi, 320);  HLOADQ(hl[5],  plo, 320);
      HLOADQ(hh[6],  phi, 384);  HLOADQ(hl[6],  plo, 384);
      HLOADQ(hh[7],  phi, 448);  HLOADQ(hl[7],  plo, 448);
      HLOADQ(hh[8],  phi, 512);  HLOADQ(hl[8],  plo, 512);
      HLOADQ(hh[9],  phi, 576);  HLOADQ(hl[9],  plo, 576);
      HLOADQ(hh[10], phi, 640);  HLOADQ(hl[10], plo, 640);
      HLOADQ(hh[11], phi, 704);  HLOADQ(hl[11], plo, 704);
      HLOADQ(hh[12], phi, 768);  HLOADQ(hl[12], plo, 768);
      HLOADQ(hh[13], phi, 832);  HLOADQ(hl[13], plo, 832);
      HLOADQ(hh[14], phi, 896);  HLOADQ(hl[14], plo, 896);
      HLOADQ(hh[15], phi, 960);  HLOADQ(hl[15], plo, 960);
      const int tn = (t + 1 < T_) ? t + 1 : t;   // uniform vmem op count
      const float* xb = xrow + tn * I_ + lk * 8;
      XLOADQ(xf0, xb, 0);   XLOADQ(xf1, xb, 16);
      XLOADQ(xf2, xb, 128); XLOADQ(xf3, xb, 144);
    }
#define MFMA_CHUNK(cc)                                                        \
    _Pragma("unroll")                                                         \
    for (int k2 = 0; k2 < 4; ++k2) {                                          \
      const int kt = (cc) * 4 + k2;                                           \
      union { u32x4 u; short8 s; } uh, ul;                                    \
      uh.u = hh[kt]; ul.u = hl[kt];                                           \
      _Pragma("unroll")                                                       \
      for (int m = 0; m < 4; ++m) {                                           \
        acc[m][0] = __builtin_amdgcn_mfma_f32_16x16x32_bf16(a_hh[m][kt], uh.s, acc[m][0], 0, 0, 0); \
        acc[m][1] = __builtin_amdgcn_mfma_f32_16x16x32_bf16(a_hh[m][kt], ul.s, acc[m][1], 0, 0, 0); \
      }                                                                       \
    }
    WAITV(28); MFMA_CHUNK(0)
    WAITV(20); MFMA_CHUNK(1)
    WAITV(12); MFMA_CHUNK(2)
    WAITV(4);  MFMA_CHUNK(3)
#undef MFMA_CHUNK

    // ---- pointwise (lane-local: 4 cells x 4 gates) ----
    float p = 0.f;
    unsigned wd[4];           // packed (hi | lo<<16) per m
#pragma unroll
    for (int m = 0; m < 4; ++m) {
      float gi = sigm(acc[m][0].x + acc[m][1].x + bias[m][0]);
      float gf = sigm(acc[m][0].y + acc[m][1].y + bias[m][1]);
      float gg = tanh_(acc[m][0].z + acc[m][1].z + bias[m][2]);
      float go = sigm(acc[m][0].w + acc[m][1].w + bias[m][3]);
      c[m] = gf * c[m] + gi * gg;
      float hv = go * tanh_(c[m]);
      p += hv * who[m];
      unsigned hb = f2bf_u(hv);
      wd[m] = hb | (f2bf_u(hv - bf2f(hb)) << 16);
    }

    // ---- in-register 4x4 transpose across lk (lanes ^16, ^32) ----
    // after: lane lk holds wd[m] = h(j = jbase + lk*4 + m)
    {
      unsigned r0[4], r1[4];
#pragma unroll
      for (int m = 0; m < 4; ++m) r0[m] = __shfl_xor(wd[m], 16);
#pragma unroll
      for (int m = 0; m < 4; ++m) if ((m ^ lk) & 1) wd[m] = r0[m ^ 1];
#pragma unroll
      for (int m = 0; m < 4; ++m) r1[m] = __shfl_xor(wd[m], 32);
#pragma unroll
      for (int m = 0; m < 4; ++m) if ((m ^ lk) & 2) wd[m] = r1[m ^ 2];
    }

    // ---- unpack planes + coalesced 8B stores (4 lanes = 32B sector) ----
    {
      unsigned hi01 = (wd[0] & 0xffffu) | (wd[1] << 16);
      unsigned hi23 = (wd[2] & 0xffffu) | (wd[3] << 16);
      unsigned lo01 = (wd[0] >> 16) | (wd[1] & 0xffff0000u);
      unsigned lo23 = (wd[2] >> 16) | (wd[3] & 0xffff0000u);
      unsigned long long hiq = (unsigned long long)hi01 | ((unsigned long long)hi23 << 32);
      unsigned long long loq = (unsigned long long)lo01 | ((unsigned long long)lo23 << 32);
      unsigned short* ph = hn + (size_t)b * H_ + jg * 64 + w * 16 + lk * 4;
      HSTORED2(ph, hiq);
      HSTORED2(ph + B_ * H_, loq);
    }

    WAITV(0);  // h stores acked at L3; x(t+1) regs ready
    if (l == 0)
      __hip_atomic_store(myflag, (unsigned)(t + 1),
                         __ATOMIC_RELAXED, __HIP_MEMORY_SCOPE_AGENT);

    // ---- projection partial (off critical path, after flag) ----
    p += __shfl_xor(p, 16);
    p += __shfl_xor(p, 32);          // sum over this wave's 16 j
    if (l < 16) atomicAdd(part + (size_t)b * T_ + t, p);
  }
}

__global__ __launch_bounds__(256) void reduce_out(const float* __restrict__ part,
                                                  const float* __restrict__ b_ho,
                                                  float* __restrict__ out) {
  int i = blockIdx.x * blockDim.x + threadIdx.x;
  if (i < B_ * T_) out[i] = part[i] + b_ho[0];
}

extern "C" void kernel_launch(void* const* d_in, const int* in_sizes, int n_in,
                              void* d_out, int out_size, void* d_ws, size_t ws_size,
                              hipStream_t stream) {
  (void)in_sizes; (void)n_in; (void)out_size; (void)ws_size;
  const float* x   = (const float*)d_in[0];
  const float* Wih = (const float*)d_in[1];
  const float* Whh = (const float*)d_in[2];
  const float* bih = (const float*)d_in[3];
  const float* bhh = (const float*)d_in[4];
  const float* Who = (const float*)d_in[5];
  const float* bho = (const float*)d_in[6];
  float* out = (float*)d_out;

  // ws: hbuf 512KB | part 256KB | flags 1KB
  unsigned short* hbuf = (unsigned short*)d_ws;
  const size_t hbytes = (size_t)2 * 2 * B_ * H_ * sizeof(unsigned short);
  float* part = (float*)((char*)d_ws + hbytes);
  const size_t pbytes = (size_t)B_ * T_ * sizeof(float);
  unsigned* flags = (unsigned*)((char*)d_ws + hbytes + pbytes);

  hipMemsetAsync(d_ws, 0, hbytes + pbytes + 8 * 32 * sizeof(unsigned), stream);

  lstm_kernel<<<dim3(64), dim3(256), 0, stream>>>(x, Wih, Whh, bih, bhh, Who,
                                                  part, hbuf, flags);
  reduce_out<<<(B_ * T_ + 255) / 256, 256, 0, stream>>>(part, bho, out);
}